// Round 1
// baseline (394.036 us; speedup 1.0000x reference)
//
#include <hip/hip_runtime.h>
#include <hip/hip_bf16.h>
#include <hip/hip_fp16.h>

#define H 8
#define B 4
#define NSEQ 2048
#define DIN 512
#define DK 64
#define DMODEL 512
#define ROWS (B*NSEQ)

typedef _Float16 f16x8 __attribute__((ext_vector_type(8)));
typedef float f32x4 __attribute__((ext_vector_type(4)));

// ---------------------------------------------------------------- prep ------
// h fp32 -> fp16; Wq/Wk/Wv [H][DIN][DK] -> Wt [3][H][DK][DIN] (transposed);
// W_out [DMODEL][DMODEL] -> Wot [e][c] (transposed).
__global__ void k_prep(const float* __restrict__ h,
                       const float* __restrict__ Wq,
                       const float* __restrict__ Wk,
                       const float* __restrict__ Wv,
                       const float* __restrict__ Wo,
                       _Float16* __restrict__ hb,
                       _Float16* __restrict__ Wt,
                       _Float16* __restrict__ Wot)
{
    const long nh = (long)ROWS * DIN;            // 4,194,304
    const long nw = (long)3 * H * DK * DIN;      //   786,432
    const long no = (long)DMODEL * DMODEL;       //   262,144
    const long total = nh + nw + no;
    for (long i = (long)blockIdx.x * blockDim.x + threadIdx.x; i < total;
         i += (long)gridDim.x * blockDim.x) {
        if (i < nh) {
            hb[i] = (_Float16)h[i];
        } else if (i < nh + nw) {
            int j = (int)(i - nh);               // [m][hh][c][d], d fastest
            int m   = j / (H * DK * DIN);
            int rem = j % (H * DK * DIN);
            int hh  = rem / (DK * DIN);
            int r2  = rem % (DK * DIN);
            int c   = r2 / DIN;
            int d   = r2 % DIN;
            const float* W = (m == 0) ? Wq : ((m == 1) ? Wk : Wv);
            Wt[j] = (_Float16)W[hh * DIN * DK + d * DK + c];
        } else {
            int j = (int)(i - nh - nw);          // Wot[e][c]
            int e = j / DMODEL;
            int c = j % DMODEL;
            Wot[j] = (_Float16)Wo[c * DMODEL + e];
        }
    }
}

// ---------------------------------------------------------------- qkv -------
// One 64x64 output tile per block (4 waves x 16 rows), K=512.
// z: 0=Q (scaled by 1/8, layout [h*B+b][n][dk])
//    1=K (layout [h*B+b][n][dk])
//    2=V (TRANSPOSED layout [h*B+b][dk][n])
__global__ __launch_bounds__(256) void k_qkv(
    const _Float16* __restrict__ hb,   // [ROWS][DIN]
    const _Float16* __restrict__ Wt,   // [3][H][DK][DIN]
    _Float16* __restrict__ Qs,
    _Float16* __restrict__ Kb,
    _Float16* __restrict__ Vt)
{
    const int rt = blockIdx.x;      // 0..127 row tile
    const int hd = blockIdx.y;      // 0..7   head
    const int m  = blockIdx.z;      // 0..2   which matrix
    const int t  = threadIdx.x;
    const int w  = t >> 6;
    const int l  = t & 63;
    const int l15 = l & 15, lg = l >> 4;

    const _Float16* A  = hb + (long)(rt*64 + w*16 + l15)*DIN + 8*lg;
    const _Float16* Wb = Wt + ((long)m*H + hd)*DK*DIN;   // [DK(c)][DIN(d)]

    f32x4 acc[4] = {};
#pragma unroll 4
    for (int ks = 0; ks < 16; ++ks) {
        f16x8 a = *(const f16x8*)(A + ks*32);
#pragma unroll
        for (int cf = 0; cf < 4; ++cf) {
            f16x8 bfr = *(const f16x8*)(Wb + (long)(cf*16 + l15)*DIN + ks*32 + 8*lg);
            acc[cf] = __builtin_amdgcn_mfma_f32_16x16x32_f16(a, bfr, acc[cf], 0, 0, 0);
        }
    }

    const int rbase = rt*64 + w*16 + lg*4;   // D rows: rbase+r, D col: cf*16+l15
#pragma unroll
    for (int cf = 0; cf < 4; ++cf) {
        const int dk = cf*16 + l15;
#pragma unroll
        for (int r = 0; r < 4; ++r) {
            const int row = rbase + r;
            const int b   = row >> 11;        // NSEQ = 2048
            const int n   = row & 2047;
            const long p  = (long)hd*B + b;
            const float v = acc[cf][r];
            if (m == 0)      Qs[(p*NSEQ + n)*DK + dk] = (_Float16)(v * 0.125f);
            else if (m == 1) Kb[(p*NSEQ + n)*DK + dk] = (_Float16)v;
            else             Vt[(p*DK + dk)*NSEQ + n] = (_Float16)v;
        }
    }
}

// ---------------------------------------------------------------- attn ------
// Flash-style: block = 64-query tile of one (head,batch) pair; 4 waves x 16 q.
// Iterate 32 key-tiles of 64. Online softmax per q-row. P redistributed via
// wave-private LDS (no cross-wave sharing -> no barriers).
__global__ __launch_bounds__(256) void k_attn(
    const _Float16* __restrict__ Qs,   // [p][n][dk], pre-scaled
    const _Float16* __restrict__ Kb,   // [p][n][dk]
    const _Float16* __restrict__ Vt,   // [p][dk][n]
    _Float16* __restrict__ heads)      // [b*NSEQ+n][DMODEL], col = hd*64+dv
{
    const int qt = blockIdx.x;   // 0..31
    const int p  = blockIdx.y;   // 0..31  (= hd*B + b)
    const int t = threadIdx.x, w = t >> 6, l = t & 63;
    const int l15 = l & 15, lg = l >> 4;

    __shared__ _Float16 Plds[4][16][72];   // per-wave [16 q][64 key], +8 pad

    const _Float16* Qp = Qs + (long)p*NSEQ*DK;
    const _Float16* Kp = Kb + (long)p*NSEQ*DK;
    const _Float16* Vp = Vt + (long)p*DK*NSEQ;

    const int qrow = qt*64 + w*16;
    const f16x8 qa0 = *(const f16x8*)(Qp + (long)(qrow + l15)*DK + 8*lg);
    const f16x8 qa1 = *(const f16x8*)(Qp + (long)(qrow + l15)*DK + 32 + 8*lg);

    float mrun[4], lrun[4];
    f32x4 acco[4] = {};
#pragma unroll
    for (int r = 0; r < 4; ++r) { mrun[r] = -1e30f; lrun[r] = 0.f; }

    for (int kt = 0; kt < 32; ++kt) {
        // ---- S = Q' K^T  (16 q x 64 keys per wave) ----
        f32x4 s[4] = {};
#pragma unroll
        for (int f = 0; f < 4; ++f) {
            const _Float16* kp = Kp + (long)(kt*64 + f*16 + l15)*DK + 8*lg;
            f16x8 k0 = *(const f16x8*)(kp);
            f16x8 k1 = *(const f16x8*)(kp + 32);
            s[f] = __builtin_amdgcn_mfma_f32_16x16x32_f16(qa0, k0, s[f], 0, 0, 0);
            s[f] = __builtin_amdgcn_mfma_f32_16x16x32_f16(qa1, k1, s[f], 0, 0, 0);
        }
        // ---- online softmax (rows live on lanes sharing lg; reduce over l15) ----
        float corr[4];
#pragma unroll
        for (int r = 0; r < 4; ++r) {
            float mx = fmaxf(fmaxf(s[0][r], s[1][r]), fmaxf(s[2][r], s[3][r]));
#pragma unroll
            for (int d = 1; d < 16; d <<= 1) mx = fmaxf(mx, __shfl_xor(mx, d));
            const float mnew = fmaxf(mrun[r], mx);
            corr[r] = __expf(mrun[r] - mnew);
            float sum = 0.f;
#pragma unroll
            for (int f = 0; f < 4; ++f) {
                const float pv = __expf(s[f][r] - mnew);
                s[f][r] = pv;
                sum += pv;
            }
#pragma unroll
            for (int d = 1; d < 16; d <<= 1) sum += __shfl_xor(sum, d);
            lrun[r] = lrun[r]*corr[r] + sum;
            mrun[r] = mnew;
        }
#pragma unroll
        for (int g = 0; g < 4; ++g)
#pragma unroll
            for (int r = 0; r < 4; ++r) acco[g][r] *= corr[r];

        // ---- P -> LDS (D-layout) then re-read as A-fragments ----
#pragma unroll
        for (int f = 0; f < 4; ++f)
#pragma unroll
            for (int r = 0; r < 4; ++r)
                Plds[w][lg*4 + r][f*16 + l15] = (_Float16)s[f][r];

        // ---- O += P V ----
#pragma unroll
        for (int kk = 0; kk < 2; ++kk) {
            f16x8 pa = *(const f16x8*)(&Plds[w][l15][kk*32 + 8*lg]);
#pragma unroll
            for (int g = 0; g < 4; ++g) {
                f16x8 vf = *(const f16x8*)(Vp + (long)(g*16 + l15)*NSEQ + kt*64 + kk*32 + 8*lg);
                acco[g] = __builtin_amdgcn_mfma_f32_16x16x32_f16(pa, vf, acco[g], 0, 0, 0);
            }
        }
    }

    // ---- epilogue: normalize + write heads (fp16) ----
    const int hd = p >> 2, b = p & 3;
    const int rbase = qt*64 + w*16 + lg*4;
#pragma unroll
    for (int r = 0; r < 4; ++r) {
        const float inv = 1.f / lrun[r];
        const int n = rbase + r;
        const long rowoff = ((long)b*NSEQ + n)*DMODEL + hd*64;
#pragma unroll
        for (int g = 0; g < 4; ++g)
            heads[rowoff + g*16 + l15] = (_Float16)(acco[g][r] * inv);
    }
}

// ---------------------------------------------------------------- out -------
__global__ __launch_bounds__(256) void k_out(
    const _Float16* __restrict__ heads,  // [ROWS][DMODEL]
    const _Float16* __restrict__ Wot,    // [e][c]
    float* __restrict__ out)             // [ROWS][DMODEL]
{
    const int rt = blockIdx.x;   // 0..127
    const int ct = blockIdx.y;   // 0..7
    const int t = threadIdx.x, w = t >> 6, l = t & 63;
    const int l15 = l & 15, lg = l >> 4;

    const _Float16* A  = heads + (long)(rt*64 + w*16 + l15)*DMODEL + 8*lg;
    const _Float16* Bw = Wot + (long)(ct*64)*DMODEL;

    f32x4 acc[4] = {};
#pragma unroll 4
    for (int ks = 0; ks < 16; ++ks) {
        f16x8 a = *(const f16x8*)(A + ks*32);
#pragma unroll
        for (int cf = 0; cf < 4; ++cf) {
            f16x8 bfr = *(const f16x8*)(Bw + (long)(cf*16 + l15)*DMODEL + ks*32 + 8*lg);
            acc[cf] = __builtin_amdgcn_mfma_f32_16x16x32_f16(a, bfr, acc[cf], 0, 0, 0);
        }
    }
    const int rbase = rt*64 + w*16 + lg*4;
#pragma unroll
    for (int cf = 0; cf < 4; ++cf) {
        const int col = ct*64 + cf*16 + l15;
#pragma unroll
        for (int r = 0; r < 4; ++r)
            out[(long)(rbase + r)*DMODEL + col] = acc[cf][r];
    }
}

// ---------------------------------------------------------------- launch ----
extern "C" void kernel_launch(void* const* d_in, const int* in_sizes, int n_in,
                              void* d_out, int out_size, void* d_ws, size_t ws_size,
                              hipStream_t stream) {
    const float* h  = (const float*)d_in[0];
    const float* Wq = (const float*)d_in[1];
    const float* Wk = (const float*)d_in[2];
    const float* Wv = (const float*)d_in[3];
    const float* Wo = (const float*)d_in[4];
    float* out = (float*)d_out;

    char* ws = (char*)d_ws;
    _Float16* hb    = (_Float16*)ws;  ws += (size_t)ROWS*DIN*2;        // 8.39 MB
    _Float16* Wt    = (_Float16*)ws;  ws += (size_t)3*H*DK*DIN*2;      // 1.57 MB
    _Float16* Wot   = (_Float16*)ws;  ws += (size_t)DMODEL*DMODEL*2;   // 0.52 MB
    _Float16* Qs    = (_Float16*)ws;  ws += (size_t)H*B*NSEQ*DK*2;     // 8.39 MB
    _Float16* Kb    = (_Float16*)ws;  ws += (size_t)H*B*NSEQ*DK*2;     // 8.39 MB
    _Float16* Vt    = (_Float16*)ws;  ws += (size_t)H*B*NSEQ*DK*2;     // 8.39 MB
    _Float16* heads = hb;  // hb dead after k_qkv; reuse for heads     // total 35.7 MB

    k_prep<<<dim3(1024), dim3(256), 0, stream>>>(h, Wq, Wk, Wv, Wo, hb, Wt, Wot);
    k_qkv <<<dim3(128, 8, 3), dim3(256), 0, stream>>>(hb, Wt, Qs, Kb, Vt);
    k_attn<<<dim3(32, 32),    dim3(256), 0, stream>>>(Qs, Kb, Vt, heads);
    k_out <<<dim3(128, 8),    dim3(256), 0, stream>>>(heads, Wot, out);
}